// Round 1
// baseline (586.269 us; speedup 1.0000x reference)
//
#include <hip/hip_runtime.h>
#include <hip/hip_bf16.h>

// B=8, T=2048, E=1024 single-head attention, bf16 MFMA pipeline, round 3:
// gemm_nt rebuilt as 256x128 tile, BK=64, 8 waves, 3-deep LDS ring with
// counted s_waitcnt vmcnt(6) (never drains in main loop) + single raw
// s_barrier per K-tile (T3+T4 from the technique catalog). Staging keeps
// global_load_lds(16B) with linear LDS dest + pre-swizzled global source;
// fragment reads keep the proven 0-conflict XOR chunk swizzle; epilogues
// and C/D layout identical to the verified round-2 kernel.
typedef __attribute__((ext_vector_type(8))) short short8;
typedef __attribute__((ext_vector_type(8))) unsigned short ushortx8;
typedef __attribute__((ext_vector_type(4))) unsigned short ushortx4;
typedef __attribute__((ext_vector_type(4))) float floatx4;

#define NB 8
#define NT 2048
#define NE 1024

__device__ __forceinline__ unsigned short f2bf(float f){
  unsigned int u = __builtin_bit_cast(unsigned int, f);
  u += 0x7FFFu + ((u >> 16) & 1u);          // RNE; inputs finite
  return (unsigned short)(u >> 16);
}
__device__ __forceinline__ float bf2f(unsigned short h){
  unsigned int u = ((unsigned int)h) << 16;
  return __builtin_bit_cast(float, u);
}

__device__ __forceinline__ void async16(void* lds, const void* g){
  __builtin_amdgcn_global_load_lds(
      (const __attribute__((address_space(1))) unsigned int*)g,
      (__attribute__((address_space(3))) unsigned int*)lds, 16, 0, 0);
}

// ---------------- fp32 -> bf16 convert, 3 sources ----------------
__global__ __launch_bounds__(256) void cvt3(const float* __restrict__ a0,
                                            const float* __restrict__ a1,
                                            const float* __restrict__ a2,
                                            unsigned short* __restrict__ out,
                                            int n4_per){
  const float* src = blockIdx.y == 0 ? a0 : (blockIdx.y == 1 ? a1 : a2);
  unsigned short* dst = out + (size_t)blockIdx.y * (size_t)n4_per * 4;
  int i = blockIdx.x * 256 + threadIdx.x;
  if (i < n4_per){
    floatx4 f = ((const floatx4*)src)[i];
    ushortx4 o;
    o.x = f2bf(f.x); o.y = f2bf(f.y); o.z = f2bf(f.z); o.w = f2bf(f.w);
    *(ushortx4*)(dst + (size_t)i * 4) = o;
  }
}

// ---------------- mask [2048][2048] int32 -> bitmask (512 KB) ----------------
__global__ __launch_bounds__(256) void pack_mask(const int* __restrict__ m,
                                                 unsigned long long* __restrict__ bits){
  int t = blockIdx.x * 256 + threadIdx.x;          // 65536 words
  const int4* p = (const int4*)(m + (size_t)t * 64);
  unsigned long long w = 0;
  #pragma unroll
  for (int jj = 0; jj < 16; jj++){
    int4 v = p[jj];
    w |= (unsigned long long)(v.x != 0) << (jj * 4 + 0);
    w |= (unsigned long long)(v.y != 0) << (jj * 4 + 1);
    w |= (unsigned long long)(v.z != 0) << (jj * 4 + 2);
    w |= (unsigned long long)(v.w != 0) << (jj * 4 + 3);
  }
  bits[t] = w;
}

// ---------------- NT GEMM: C[m,n] = sum_k A[m,k]*B[n,k], all bf16 in ----------------
// Tile 256x128, BK=64, 512 threads = 8 waves as 4(M) x 2(N); each wave owns a
// 64x64 output tile = acc[4][4] of 16x16x32 MFMAs (same as verified round-2).
// LDS: 3-buffer ring, A 3x32KB + B 3x16KB = 144 KB. Pipeline: at K-tile t,
// issue stage of t+2 (6 x global_load_lds dwordx4), compute t, then
// "s_waitcnt vmcnt(6); s_barrier" -> t+1 resident, t+2 still in flight.
// Safety: buffer (t+2)%3 was last read at K-tile t-1, strictly before the
// barrier that precedes this stage issue -> no read/overwrite race.
// EPI 0: store bf16. EPI 1: mask-bit ? v/32 : -inf, store bf16. EPI 2: fp32.
template<int EPI>
__global__ __launch_bounds__(512, 2) void gemm_nt(
    const unsigned short* __restrict__ A, long strideA,
    const unsigned short* __restrict__ B, long strideB,
    void* __restrict__ Out, long strideOutBytes,
    const unsigned long long* __restrict__ mbits,
    int K, int gx, int gy)
{
  __shared__ __attribute__((aligned(16))) unsigned short As[3 * 256 * 64];  // 96 KB
  __shared__ __attribute__((aligned(16))) unsigned short Bs[3 * 128 * 64];  // 48 KB
  const int tid = threadIdx.x;
  const int lane = tid & 63, wave = tid >> 6;

  // XCD-aware decode: L%8 = XCD; all gx n-tiles of one A-strip on one XCD.
  int L = blockIdx.x;
  int xcd = L & 7, tt = L >> 3;
  int x = tt % gx;
  int strip = xcd + ((tt / gx) << 3);
  int y = strip % gy, z = strip / gy;
  const int m0 = y << 8, n0 = x << 7;
  const int Nn = gx << 7;

  const unsigned short* Az = A + (size_t)z * strideA;
  const unsigned short* Bz = B + (size_t)z * strideB;

  // Staging addresses. A tile = 2048 16B-slots (256 rows x 8 chunks), 4/thread.
  // B tile = 1024 slots (128 rows x 8 chunks), 2/thread. Slot s: wave-uniform
  // base + lane*16 (global_load_lds requirement). Inverse swizzle on the
  // GLOBAL side: row = s>>3, chunk = (s&7) ^ (row&7).
  const char* gA[4]; int loA[4];
  #pragma unroll
  for (int i = 0; i < 4; i++){
    int s = (wave << 8) + (i << 6) + lane;
    int row = s >> 3, c = (s & 7) ^ (row & 7);
    loA[i] = s << 4;
    gA[i] = (const char*)(Az + (size_t)(m0 + row) * K) + (c << 4);
  }
  const char* gB[2]; int loB[2];
  #pragma unroll
  for (int i = 0; i < 2; i++){
    int s = (wave << 7) + (i << 6) + lane;
    int row = s >> 3, c = (s & 7) ^ (row & 7);
    loB[i] = s << 4;
    gB[i] = (const char*)(Bz + (size_t)(n0 + row) * K) + (c << 4);
  }
  char* AsB = (char*)As;
  char* BsB = (char*)Bs;

  // Fragment-read bases (within one buffer): row r, chunk h at byte
  // r*128 + ((h ^ (r&7))<<4) -> 2-way (free) bank pattern, measured 0 conflicts.
  const int lm = lane & 15, qd = lane >> 4;
  const int wr = (wave >> 1) << 6, wc = (wave & 1) << 6;   // wave = 4(M) x 2(N)
  const int sw = lm & 7;
  const int offA0 = (wr + lm) * 128 + ((qd ^ sw) << 4);
  const int offA1 = (wr + lm) * 128 + (((4 + qd) ^ sw) << 4);
  const int offB0 = (wc + lm) * 128 + ((qd ^ sw) << 4);
  const int offB1 = (wc + lm) * 128 + (((4 + qd) ^ sw) << 4);

  floatx4 acc[4][4];
  floatx4 zero4 = {0.f, 0.f, 0.f, 0.f};
  #pragma unroll
  for (int a = 0; a < 4; a++)
    #pragma unroll
    for (int b = 0; b < 4; b++) acc[a][b] = zero4;

  auto stage = [&](int buf){
    char* Ad = AsB + (buf << 15);
    char* Bd = BsB + (buf << 14);
    #pragma unroll
    for (int i = 0; i < 4; i++){ async16(Ad + loA[i], gA[i]); gA[i] += 128; }
    #pragma unroll
    for (int i = 0; i < 2; i++){ async16(Bd + loB[i], gB[i]); gB[i] += 128; }
  };

  auto compute = [&](int b){
    const char* ab = AsB + (b << 15);
    const char* bb = BsB + (b << 14);
    short8 a0[4], a1[4], b0[4], b1[4];
    #pragma unroll
    for (int mi = 0; mi < 4; mi++) a0[mi] = *(const short8*)(ab + offA0 + mi * 2048);
    #pragma unroll
    for (int ni = 0; ni < 4; ni++) b0[ni] = *(const short8*)(bb + offB0 + ni * 2048);
    __builtin_amdgcn_s_setprio(1);
    #pragma unroll
    for (int mi = 0; mi < 4; mi++)
      #pragma unroll
      for (int ni = 0; ni < 4; ni++)
        acc[mi][ni] = __builtin_amdgcn_mfma_f32_16x16x32_bf16(a0[mi], b0[ni], acc[mi][ni], 0, 0, 0);
    __builtin_amdgcn_s_setprio(0);
    #pragma unroll
    for (int mi = 0; mi < 4; mi++) a1[mi] = *(const short8*)(ab + offA1 + mi * 2048);
    #pragma unroll
    for (int ni = 0; ni < 4; ni++) b1[ni] = *(const short8*)(bb + offB1 + ni * 2048);
    __builtin_amdgcn_s_setprio(1);
    #pragma unroll
    for (int mi = 0; mi < 4; mi++)
      #pragma unroll
      for (int ni = 0; ni < 4; ni++)
        acc[mi][ni] = __builtin_amdgcn_mfma_f32_16x16x32_bf16(a1[mi], b1[ni], acc[mi][ni], 0, 0, 0);
    __builtin_amdgcn_s_setprio(0);
  };

  const int NK = K >> 6;           // 16 or 32 here; needs NK >= 3
  stage(0);
  stage(1);
  // t0's 6 loads complete; t1's 6 stay in flight.
  asm volatile("s_waitcnt vmcnt(6)\n\ts_barrier" ::: "memory");

  int b = 0, bs = 2;
  for (int t = 0; t < NK - 2; ++t){
    stage(bs);                     // K-tile t+2 -> buffer last read at t-1
    compute(b);                    // K-tile t
    // Wait for t+1's 6 loads (issued last iteration); t+2's 6 stay in flight.
    asm volatile("s_waitcnt vmcnt(6)\n\ts_barrier" ::: "memory");
    b  = (b  == 2) ? 0 : b  + 1;
    bs = (bs == 2) ? 0 : bs + 1;
  }
  compute(b);                      // K-tile NK-2 (nothing left to stage)
  asm volatile("s_waitcnt vmcnt(0)\n\ts_barrier" ::: "memory");
  b = (b == 2) ? 0 : b + 1;
  compute(b);                      // K-tile NK-1

  // Epilogue. C/D layout: col = lane&15, row = (lane>>4)*4 + i  (m89/m91).
  char* OutZ = (char*)Out + (size_t)z * strideOutBytes;
  if constexpr (EPI == 1){
    int wcol = (n0 + wc) >> 6;
    #pragma unroll
    for (int mi = 0; mi < 4; mi++){
      #pragma unroll
      for (int i = 0; i < 4; i++){
        int row = m0 + wr + mi * 16 + qd * 4 + i;
        unsigned long long w = mbits[(size_t)row * (NT / 64) + wcol];
        unsigned short* po = (unsigned short*)OutZ + (size_t)row * Nn + n0 + wc;
        #pragma unroll
        for (int ni = 0; ni < 4; ni++){
          float vv = acc[mi][ni][i];
          float s = ((w >> (ni * 16 + lm)) & 1ull) ? vv * 0.03125f : -INFINITY;
          po[ni * 16 + lm] = f2bf(s);
        }
      }
    }
  } else {
    #pragma unroll
    for (int mi = 0; mi < 4; mi++){
      #pragma unroll
      for (int i = 0; i < 4; i++){
        int row = m0 + wr + mi * 16 + qd * 4 + i;
        #pragma unroll
        for (int ni = 0; ni < 4; ni++){
          int col = n0 + wc + ni * 16 + lm;
          float vv = acc[mi][ni][i];
          if constexpr (EPI == 0)
            ((unsigned short*)OutZ)[(size_t)row * Nn + col] = f2bf(vv);
          else
            ((float*)OutZ)[(size_t)row * Nn + col] = vv;
        }
      }
    }
  }
}

// ---------------- bf16 transpose (per batch): [rows][cols] -> [cols][rows] ----------------
__global__ __launch_bounds__(256) void transpose_bf16(const unsigned short* __restrict__ in,
                                                      unsigned short* __restrict__ out,
                                                      int rows, int cols){
  __shared__ __attribute__((aligned(16))) unsigned short tile[64][72];
  const unsigned short* ib = in + (size_t)blockIdx.z * rows * cols;
  unsigned short* ob = out + (size_t)blockIdx.z * rows * cols;
  int r0 = blockIdx.x * 64;
  int c0 = blockIdx.y * 64;
  int tid = threadIdx.x;
  #pragma unroll
  for (int i = 0; i < 2; i++){
    int id = tid + i * 256;
    int r = id >> 3, c = (id & 7) * 8;
    ushortx8 v = *(const ushortx8*)(ib + (size_t)(r0 + r) * cols + c0 + c);
    *(ushortx8*)&tile[r][c] = v;
  }
  __syncthreads();
  #pragma unroll
  for (int i = 0; i < 2; i++){
    int id = tid + i * 256;
    int r = id >> 3, c = (id & 7) * 8;
    ushortx8 v;
    #pragma unroll
    for (int j = 0; j < 8; j++) v[j] = tile[c + j][r];
    *(ushortx8*)(ob + (size_t)(c0 + r) * rows + r0 + c) = v;
  }
}

// ---------------- row softmax, in place over bf16 scores ----------------
__global__ __launch_bounds__(256) void softmax_rows(unsigned short* __restrict__ S){
  size_t row = blockIdx.x;
  unsigned short* p = S + row * NT;
  int tid = threadIdx.x;
  ushortx8 v = *(const ushortx8*)(p + tid * 8);
  float f[8];
  #pragma unroll
  for (int j = 0; j < 8; j++) f[j] = bf2f(v[j]);
  float mx = f[0];
  #pragma unroll
  for (int j = 1; j < 8; j++) mx = fmaxf(mx, f[j]);
  #pragma unroll
  for (int off = 32; off > 0; off >>= 1) mx = fmaxf(mx, __shfl_xor(mx, off, 64));
  __shared__ float redm[4], reds[4];
  int lane = tid & 63, wv = tid >> 6;
  if (lane == 0) redm[wv] = mx;
  __syncthreads();
  mx = fmaxf(fmaxf(redm[0], redm[1]), fmaxf(redm[2], redm[3]));
  float e[8]; float se = 0.f;
  #pragma unroll
  for (int j = 0; j < 8; j++){ e[j] = __expf(f[j] - mx); se += e[j]; }
  #pragma unroll
  for (int off = 32; off > 0; off >>= 1) se += __shfl_xor(se, off, 64);
  if (lane == 0) reds[wv] = se;
  __syncthreads();
  se = reds[0] + reds[1] + reds[2] + reds[3];
  float inv = 1.f / se;
  ushortx8 o;
  #pragma unroll
  for (int j = 0; j < 8; j++) o[j] = f2bf(e[j] * inv);
  *(ushortx8*)(p + tid * 8) = o;
}

extern "C" void kernel_launch(void* const* d_in, const int* in_sizes, int n_in,
                              void* d_out, int out_size, void* d_ws, size_t ws_size,
                              hipStream_t stream){
  const float* q  = (const float*)d_in[0];
  const float* k  = (const float*)d_in[1];
  const float* v  = (const float*)d_in[2];
  const int* mask = (const int*)d_in[3];
  const float* Wq = (const float*)d_in[4];
  const float* Wk = (const float*)d_in[5];
  const float* Wv = (const float*)d_in[6];

  const size_t BTE = (size_t)NB * NT * NE;     // 16,777,216
  unsigned short* ws   = (unsigned short*)d_ws;
  unsigned short* QKVp = ws;                                    // [3][B*T][E]
  unsigned short* VpT  = ws + 3 * BTE;                          // [B][E][T]
  unsigned short* Sb   = ws + 3 * BTE + BTE;                    // [B][T][T]
  unsigned short* Qin  = ws + 3 * BTE;                          // aliases VpT+Sb (3*BTE)
  unsigned short* Wb   = ws + 3 * BTE + BTE + (size_t)NB * NT * NT;  // [3][E][E]
  unsigned long long* mbits = (unsigned long long*)(Wb + (size_t)3 * NE * NE);

  unsigned short* Qp = QKVp;
  unsigned short* Kp = QKVp + BTE;
  unsigned short* Vp = QKVp + 2 * BTE;

  // 1) fp32 -> bf16: inputs q,k,v (Qin aliases the region later used by VpT|Sb)
  cvt3<<<dim3(16384, 3), 256, 0, stream>>>(q, k, v, Qin, (int)(BTE / 4));
  // 2) weights -> bf16
  cvt3<<<dim3(1024, 3), 256, 0, stream>>>(Wq, Wk, Wv, Wb, NE * NE / 4);
  // 3) mask -> bitmask
  pack_mask<<<256, 256, 0, stream>>>(mask, mbits);

  // 4) projections: [3 x] (16384 x 1024 x 1024); gx=8, gy=64, gz=3
  gemm_nt<0><<<1536, 512, 0, stream>>>(
      Qin, (long)BTE, Wb, (long)NE * NE,
      QKVp, (long)BTE * 2, nullptr, NE, 8, 64);

  // 5) V -> V^T per batch (overwrites Qin's q-part, no longer needed)
  transpose_bf16<<<dim3(32, 16, 8), 256, 0, stream>>>(Vp, VpT, NT, NE);

  // 6) S = mask ? QK^T/32 : -inf; gx=16, gy=8, gz=8
  gemm_nt<1><<<1024, 512, 0, stream>>>(
      Qp, (long)NT * NE, Kp, (long)NT * NE,
      Sb, (long)NT * NT * 2, mbits, NE, 16, 8);

  // 7) softmax rows, in place
  softmax_rows<<<dim3(NB * NT), 256, 0, stream>>>(Sb);

  // 8) O = P V; gx=8, gy=8, gz=8, fp32 out
  gemm_nt<2><<<512, 512, 0, stream>>>(
      Sb, (long)NT * NT, VpT, (long)NE * NT,
      d_out, (long)NT * NE * 4, nullptr, NT, 8, 8);
}

// Round 2
// 525.805 us; speedup vs baseline: 1.1150x; 1.1150x over previous
//
#include <hip/hip_runtime.h>
#include <hip/hip_bf16.h>

// B=8, T=2048, E=1024 single-head attention, bf16 MFMA pipeline, round 4:
// gemm_nt rebuilt on the verified 256x256 8-phase schedule (T2+T3+T4+T5):
// BK=64, 8 waves (2Mx4N), LDS 128 KB = 2 dbuf x {A,B} x {k0,k1} 16KB units,
// 4 phases per K-tile each {stage 1 unit, ds_read frags, lgkm0+barrier,
// setprio 16xMFMA}, single counted vmcnt(6) per K-tile (never drains in
// main loop; 3 units of t+2 stay in flight => ~2000+ cyc prefetch margin).
typedef __attribute__((ext_vector_type(8))) short short8;
typedef __attribute__((ext_vector_type(8))) unsigned short ushortx8;
typedef __attribute__((ext_vector_type(4))) unsigned short ushortx4;
typedef __attribute__((ext_vector_type(4))) float floatx4;

#define NB 8
#define NT 2048
#define NE 1024

__device__ __forceinline__ unsigned short f2bf(float f){
  unsigned int u = __builtin_bit_cast(unsigned int, f);
  u += 0x7FFFu + ((u >> 16) & 1u);          // RNE; inputs finite
  return (unsigned short)(u >> 16);
}
__device__ __forceinline__ float bf2f(unsigned short h){
  unsigned int u = ((unsigned int)h) << 16;
  return __builtin_bit_cast(float, u);
}

__device__ __forceinline__ void async16(void* lds, const void* g){
  __builtin_amdgcn_global_load_lds(
      (const __attribute__((address_space(1))) unsigned int*)g,
      (__attribute__((address_space(3))) unsigned int*)lds, 16, 0, 0);
}

#define MFMA16(d, va, vb) \
  d = __builtin_amdgcn_mfma_f32_16x16x32_bf16(va, vb, d, 0, 0, 0)

// ---------------- fp32 -> bf16 convert, 3 sources ----------------
__global__ __launch_bounds__(256) void cvt3(const float* __restrict__ a0,
                                            const float* __restrict__ a1,
                                            const float* __restrict__ a2,
                                            unsigned short* __restrict__ out,
                                            int n4_per){
  const float* src = blockIdx.y == 0 ? a0 : (blockIdx.y == 1 ? a1 : a2);
  unsigned short* dst = out + (size_t)blockIdx.y * (size_t)n4_per * 4;
  int i = blockIdx.x * 256 + threadIdx.x;
  if (i < n4_per){
    floatx4 f = ((const floatx4*)src)[i];
    ushortx4 o;
    o.x = f2bf(f.x); o.y = f2bf(f.y); o.z = f2bf(f.z); o.w = f2bf(f.w);
    *(ushortx4*)(dst + (size_t)i * 4) = o;
  }
}

// ---------------- mask [2048][2048] int32 -> bitmask (512 KB) ----------------
__global__ __launch_bounds__(256) void pack_mask(const int* __restrict__ m,
                                                 unsigned long long* __restrict__ bits){
  int t = blockIdx.x * 256 + threadIdx.x;          // 65536 words
  const int4* p = (const int4*)(m + (size_t)t * 64);
  unsigned long long w = 0;
  #pragma unroll
  for (int jj = 0; jj < 16; jj++){
    int4 v = p[jj];
    w |= (unsigned long long)(v.x != 0) << (jj * 4 + 0);
    w |= (unsigned long long)(v.y != 0) << (jj * 4 + 1);
    w |= (unsigned long long)(v.z != 0) << (jj * 4 + 2);
    w |= (unsigned long long)(v.w != 0) << (jj * 4 + 3);
  }
  bits[t] = w;
}

// ---------------- NT GEMM: C[m,n] = sum_k A[m,k]*B[n,k], all bf16 in ----------------
// Tile 256x256, BK=64, 512 threads = 8 waves (wm=wave>>2 in M, wn=wave&3 in N);
// per-wave 128x64 output = acc[8][4] of 16x16x32 MFMAs.
// LDS 128 KB: [dbuf][A|B][khalf] 16 KB units, rows of 64 B (32 bf16), chunk
// swizzle c_store = c ^ (r&3) -> fragment ds_read_b128 covers all 32 banks
// evenly (0 conflicts); staging is linear-LDS global_load_lds with the
// inverse swizzle applied to the per-lane GLOBAL address.
// Schedule per K-tile t (4 phases, buf p=t&1):
//   p1: stage A-k1(t+1)->p^1 | read a(k0,mi0-3)+b(k0) | lgkm0+bar | 16 MFMA
//   p2: stage B-k0(t+2)->p   | read a(k0,mi4-7)       | lgkm0+bar | 16 MFMA
//   p3: stage A-k0(t+2)->p   | read a(k1,mi0-3)+b(k1) | lgkm0+bar | 16 MFMA
//   p4: stage B-k1(t+2)->p   | read a(k1,mi4-7)       | vmcnt(6)+lgkm0+bar | 16 MFMA
// vmcnt(6) at p4 confirms ALL 4 units of t+1 (8 loads), leaves 3 units of
// t+2 in flight. lgkmcnt(0) precedes each barrier so a unit staged in phase
// p is guaranteed past all waves' reads of its previous occupant (freed at
// phase p-1's barrier).
// EPI 0: store bf16. EPI 1: mask-bit ? v/32 : -inf, store bf16. EPI 2: fp32.
template<int EPI>
__global__ __launch_bounds__(512, 2) void gemm_nt(
    const unsigned short* __restrict__ A, long strideA,
    const unsigned short* __restrict__ B, long strideB,
    void* __restrict__ Out, long strideOutBytes,
    const unsigned long long* __restrict__ mbits,
    int K, int gx, int gy)
{
  __shared__ __attribute__((aligned(16))) char Lds[131072];
  const int tid = threadIdx.x;
  const int lane = tid & 63, wave = tid >> 6;

  // XCD-aware decode: L%8 = XCD; all gx n-tiles of one A-strip on one XCD.
  int L = blockIdx.x;
  int xcd = L & 7, tt = L >> 3;
  int x = tt % gx;
  int strip = xcd + ((tt / gx) << 3);
  int y = strip % gy, z = strip / gy;
  const int m0 = y << 8, n0 = x << 8;
  const int Nn = gx << 8;

  const unsigned short* Az = A + (size_t)z * strideA;
  const unsigned short* Bz = B + (size_t)z * strideB;

  // Staging: unit = 16 KB = 1024 slots of 16B; thread covers slots tid and
  // tid+512. slot s: r = s>>2 (row, +128 for i=1), cs = tid&3,
  // logical chunk c = cs ^ (r&3)  [r&3 invariant under +128].
  const long rowb  = (long)K * 2;       // bytes per A/B row
  const long rs128 = rowb << 7;         // 128 rows
  const int r0 = tid >> 2;
  const int c0 = (tid & 3) ^ (r0 & 3);
  const char* pA0 = (const char*)Az + (size_t)(m0 + r0) * rowb + (c0 << 4);      // k-half 0
  const char* pA1 = pA0 + 64;                                                    // k-half 1
  const char* pB0 = (const char*)Bz + (size_t)(n0 + r0) * rowb + (c0 << 4);
  const char* pB1 = pB0 + 64;
  const int stg = tid << 4;

  auto stageU = [&](const char*& g, int ldsoff){
    async16(Lds + ldsoff + stg,        g);
    async16(Lds + ldsoff + stg + 8192, g + rs128);
    g += 128;                           // advance one K-tile (BK=64 bf16)
  };

  // Fragment reads: A row (wm*128 + mi*16 + lm), chunk qd, swizzled slot
  // qd ^ (row&3) = qd ^ (lm&3). 64-B rows -> all 32 banks covered evenly.
  const int lm = lane & 15, qd = lane >> 4;
  const int wm = wave >> 2, wn = wave & 3;          // 2 (M) x 4 (N)
  const int fsw  = (qd ^ (lm & 3)) << 4;
  const int aoff = ((wm << 7) + lm) * 64 + fsw;               // + mi*1024 + kh*16384 + dbuf
  const int boff = 32768 + ((wn << 6) + lm) * 64 + fsw;       // + ni*1024 + kh*16384 + dbuf

  floatx4 acc[8][4];
  floatx4 zero4 = {0.f, 0.f, 0.f, 0.f};
  #pragma unroll
  for (int a = 0; a < 8; a++)
    #pragma unroll
    for (int b = 0; b < 4; b++) acc[a][b] = zero4;

  const int NK = K >> 6;

  // Prologue: tile0 all 4 units, tile1 {B-k0, A-k0, B-k1} (A-k1(1) comes at
  // t=0.p1). vmcnt(6) confirms tile0's 8 loads, leaves tile1's 6 in flight.
  stageU(pB0, 32768);                     // B-k0(0) dbuf0
  stageU(pA0, 0);                         // A-k0(0)
  stageU(pB1, 32768 + 16384);             // B-k1(0)
  stageU(pA1, 16384);                     // A-k1(0)
  stageU(pB0, 65536 + 32768);             // B-k0(1) dbuf1
  stageU(pA0, 65536);                     // A-k0(1)
  stageU(pB1, 65536 + 32768 + 16384);     // B-k1(1)
  asm volatile("s_waitcnt vmcnt(6)\n\ts_barrier" ::: "memory");

  short8 a[4], b[4];
  for (int t = 0; t < NK; ++t){
    const int rb = (t & 1) << 16;         // read dbuf (and t+2 stage dbuf)
    const int sb = rb ^ 65536;            // t+1 stage dbuf

    // ---- phase 1: kh=0, mi 0-3 (+ all B kh=0) ----
    if (t + 1 < NK) stageU(pA1, sb + 16384);
    #pragma unroll
    for (int j = 0; j < 4; j++) a[j] = *(const short8*)(Lds + rb + aoff + j * 1024);
    #pragma unroll
    for (int n = 0; n < 4; n++) b[n] = *(const short8*)(Lds + rb + boff + n * 1024);
    asm volatile("s_waitcnt lgkmcnt(0)\n\ts_barrier" ::: "memory");
    __builtin_amdgcn_sched_barrier(0);
    __builtin_amdgcn_s_setprio(1);
    #pragma unroll
    for (int j = 0; j < 4; j++)
      #pragma unroll
      for (int n = 0; n < 4; n++) MFMA16(acc[j][n], a[j], b[n]);
    __builtin_amdgcn_s_setprio(0);

    // ---- phase 2: kh=0, mi 4-7 ----
    if (t + 2 < NK) stageU(pB0, rb + 32768);
    #pragma unroll
    for (int j = 0; j < 4; j++) a[j] = *(const short8*)(Lds + rb + aoff + (4 + j) * 1024);
    asm volatile("s_waitcnt lgkmcnt(0)\n\ts_barrier" ::: "memory");
    __builtin_amdgcn_sched_barrier(0);
    __builtin_amdgcn_s_setprio(1);
    #pragma unroll
    for (int j = 0; j < 4; j++)
      #pragma unroll
      for (int n = 0; n < 4; n++) MFMA16(acc[4 + j][n], a[j], b[n]);
    __builtin_amdgcn_s_setprio(0);

    // ---- phase 3: kh=1, mi 0-3 (+ all B kh=1) ----
    if (t + 2 < NK) stageU(pA0, rb);
    #pragma unroll
    for (int j = 0; j < 4; j++) a[j] = *(const short8*)(Lds + rb + 16384 + aoff + j * 1024);
    #pragma unroll
    for (int n = 0; n < 4; n++) b[n] = *(const short8*)(Lds + rb + 16384 + boff + n * 1024);
    asm volatile("s_waitcnt lgkmcnt(0)\n\ts_barrier" ::: "memory");
    __builtin_amdgcn_sched_barrier(0);
    __builtin_amdgcn_s_setprio(1);
    #pragma unroll
    for (int j = 0; j < 4; j++)
      #pragma unroll
      for (int n = 0; n < 4; n++) MFMA16(acc[j][n], a[j], b[n]);
    __builtin_amdgcn_s_setprio(0);

    // ---- phase 4: kh=1, mi 4-7; the one counted vmcnt per K-tile ----
    if (t + 2 < NK) stageU(pB1, rb + 32768 + 16384);
    #pragma unroll
    for (int j = 0; j < 4; j++) a[j] = *(const short8*)(Lds + rb + 16384 + aoff + (4 + j) * 1024);
    if (t + 2 < NK)
      asm volatile("s_waitcnt vmcnt(6) lgkmcnt(0)\n\ts_barrier" ::: "memory");
    else
      asm volatile("s_waitcnt vmcnt(0) lgkmcnt(0)\n\ts_barrier" ::: "memory");
    __builtin_amdgcn_sched_barrier(0);
    __builtin_amdgcn_s_setprio(1);
    #pragma unroll
    for (int j = 0; j < 4; j++)
      #pragma unroll
      for (int n = 0; n < 4; n++) MFMA16(acc[4 + j][n], a[j], b[n]);
    __builtin_amdgcn_s_setprio(0);
  }

  // Epilogue. C/D layout: col = lane&15, row = (lane>>4)*4 + i  (m89/m91).
  char* OutZ = (char*)Out + (size_t)z * strideOutBytes;
  const int colbase = n0 + (wn << 6);
  if constexpr (EPI == 1){
    const int wcol = colbase >> 6;
    #pragma unroll
    for (int mi = 0; mi < 8; mi++){
      #pragma unroll
      for (int i = 0; i < 4; i++){
        int row = m0 + (wm << 7) + mi * 16 + qd * 4 + i;
        unsigned long long w = mbits[(size_t)row * (NT / 64) + wcol];
        unsigned short* po = (unsigned short*)OutZ + (size_t)row * Nn + colbase;
        #pragma unroll
        for (int ni = 0; ni < 4; ni++){
          float vv = acc[mi][ni][i];
          float s = ((w >> (ni * 16 + lm)) & 1ull) ? vv * 0.03125f : -INFINITY;
          po[ni * 16 + lm] = f2bf(s);
        }
      }
    }
  } else {
    #pragma unroll
    for (int mi = 0; mi < 8; mi++){
      #pragma unroll
      for (int i = 0; i < 4; i++){
        int row = m0 + (wm << 7) + mi * 16 + qd * 4 + i;
        #pragma unroll
        for (int ni = 0; ni < 4; ni++){
          int col = colbase + ni * 16 + lm;
          float vv = acc[mi][ni][i];
          if constexpr (EPI == 0)
            ((unsigned short*)OutZ)[(size_t)row * Nn + col] = f2bf(vv);
          else
            ((float*)OutZ)[(size_t)row * Nn + col] = vv;
        }
      }
    }
  }
}

// ---------------- bf16 transpose (per batch): [rows][cols] -> [cols][rows] ----------------
__global__ __launch_bounds__(256) void transpose_bf16(const unsigned short* __restrict__ in,
                                                      unsigned short* __restrict__ out,
                                                      int rows, int cols){
  __shared__ __attribute__((aligned(16))) unsigned short tile[64][72];
  const unsigned short* ib = in + (size_t)blockIdx.z * rows * cols;
  unsigned short* ob = out + (size_t)blockIdx.z * rows * cols;
  int r0 = blockIdx.x * 64;
  int c0 = blockIdx.y * 64;
  int tid = threadIdx.x;
  #pragma unroll
  for (int i = 0; i < 2; i++){
    int id = tid + i * 256;
    int r = id >> 3, c = (id & 7) * 8;
    ushortx8 v = *(const ushortx8*)(ib + (size_t)(r0 + r) * cols + c0 + c);
    *(ushortx8*)&tile[r][c] = v;
  }
  __syncthreads();
  #pragma unroll
  for (int i = 0; i < 2; i++){
    int id = tid + i * 256;
    int r = id >> 3, c = (id & 7) * 8;
    ushortx8 v;
    #pragma unroll
    for (int j = 0; j < 8; j++) v[j] = tile[c + j][r];
    *(ushortx8*)(ob + (size_t)(c0 + r) * rows + r0 + c) = v;
  }
}

// ---------------- row softmax, in place over bf16 scores ----------------
__global__ __launch_bounds__(256) void softmax_rows(unsigned short* __restrict__ S){
  size_t row = blockIdx.x;
  unsigned short* p = S + row * NT;
  int tid = threadIdx.x;
  ushortx8 v = *(const ushortx8*)(p + tid * 8);
  float f[8];
  #pragma unroll
  for (int j = 0; j < 8; j++) f[j] = bf2f(v[j]);
  float mx = f[0];
  #pragma unroll
  for (int j = 1; j < 8; j++) mx = fmaxf(mx, f[j]);
  #pragma unroll
  for (int off = 32; off > 0; off >>= 1) mx = fmaxf(mx, __shfl_xor(mx, off, 64));
  __shared__ float redm[4], reds[4];
  int lane = tid & 63, wv = tid >> 6;
  if (lane == 0) redm[wv] = mx;
  __syncthreads();
  mx = fmaxf(fmaxf(redm[0], redm[1]), fmaxf(redm[2], redm[3]));
  float e[8]; float se = 0.f;
  #pragma unroll
  for (int j = 0; j < 8; j++){ e[j] = __expf(f[j] - mx); se += e[j]; }
  #pragma unroll
  for (int off = 32; off > 0; off >>= 1) se += __shfl_xor(se, off, 64);
  if (lane == 0) reds[wv] = se;
  __syncthreads();
  se = reds[0] + reds[1] + reds[2] + reds[3];
  float inv = 1.f / se;
  ushortx8 o;
  #pragma unroll
  for (int j = 0; j < 8; j++) o[j] = f2bf(e[j] * inv);
  *(ushortx8*)(p + tid * 8) = o;
}

extern "C" void kernel_launch(void* const* d_in, const int* in_sizes, int n_in,
                              void* d_out, int out_size, void* d_ws, size_t ws_size,
                              hipStream_t stream){
  const float* q  = (const float*)d_in[0];
  const float* k  = (const float*)d_in[1];
  const float* v  = (const float*)d_in[2];
  const int* mask = (const int*)d_in[3];
  const float* Wq = (const float*)d_in[4];
  const float* Wk = (const float*)d_in[5];
  const float* Wv = (const float*)d_in[6];

  const size_t BTE = (size_t)NB * NT * NE;     // 16,777,216
  unsigned short* ws   = (unsigned short*)d_ws;
  unsigned short* QKVp = ws;                                    // [3][B*T][E]
  unsigned short* VpT  = ws + 3 * BTE;                          // [B][E][T]
  unsigned short* Sb   = ws + 3 * BTE + BTE;                    // [B][T][T]
  unsigned short* Qin  = ws + 3 * BTE;                          // aliases VpT+Sb (3*BTE)
  unsigned short* Wb   = ws + 3 * BTE + BTE + (size_t)NB * NT * NT;  // [3][E][E]
  unsigned long long* mbits = (unsigned long long*)(Wb + (size_t)3 * NE * NE);

  unsigned short* Qp = QKVp;
  unsigned short* Kp = QKVp + BTE;
  unsigned short* Vp = QKVp + 2 * BTE;

  // 1) fp32 -> bf16: inputs q,k,v (Qin aliases the region later used by VpT|Sb)
  cvt3<<<dim3(16384, 3), 256, 0, stream>>>(q, k, v, Qin, (int)(BTE / 4));
  // 2) weights -> bf16
  cvt3<<<dim3(1024, 3), 256, 0, stream>>>(Wq, Wk, Wv, Wb, NE * NE / 4);
  // 3) mask -> bitmask
  pack_mask<<<256, 256, 0, stream>>>(mask, mbits);

  // 4) projections: [3 x] (16384 x 1024 x 1024); gx=4, gy=64, gz=3
  gemm_nt<0><<<768, 512, 0, stream>>>(
      Qin, (long)BTE, Wb, (long)NE * NE,
      QKVp, (long)BTE * 2, nullptr, NE, 4, 64);

  // 5) V -> V^T per batch (overwrites Qin's q-part, no longer needed)
  transpose_bf16<<<dim3(32, 16, 8), 256, 0, stream>>>(Vp, VpT, NT, NE);

  // 6) S = mask ? QK^T/32 : -inf; gx=8, gy=8, gz=8
  gemm_nt<1><<<512, 512, 0, stream>>>(
      Qp, (long)NT * NE, Kp, (long)NT * NE,
      Sb, (long)NT * NT * 2, mbits, NE, 8, 8);

  // 7) softmax rows, in place
  softmax_rows<<<dim3(NB * NT), 256, 0, stream>>>(Sb);

  // 8) O = P V; gx=4, gy=8, gz=8, fp32 out
  gemm_nt<2><<<256, 512, 0, stream>>>(
      Sb, (long)NT * NT, VpT, (long)NE * NT,
      d_out, (long)NT * NE * 4, nullptr, NT, 4, 8);
}

// Round 3
// 499.903 us; speedup vs baseline: 1.1728x; 1.0518x over previous
//
#include <hip/hip_runtime.h>
#include <hip/hip_bf16.h>

// B=8, T=2048, E=1024 single-head attention, bf16 MFMA pipeline, round 5:
// identical to round-4 8-phase 256x256 schedule, with the LDS chunk swizzle
// corrected from c^(row&3) to c^((row>>1)&3): each consecutive-8-lane group
// of a ds_read_b128 now covers all eight 16B slots of a 128B bank row
// (round-4 measured 9.4M SQ_LDS_BANK_CONFLICT from the broken variant).
typedef __attribute__((ext_vector_type(8))) short short8;
typedef __attribute__((ext_vector_type(8))) unsigned short ushortx8;
typedef __attribute__((ext_vector_type(4))) unsigned short ushortx4;
typedef __attribute__((ext_vector_type(4))) float floatx4;

#define NB 8
#define NT 2048
#define NE 1024

__device__ __forceinline__ unsigned short f2bf(float f){
  unsigned int u = __builtin_bit_cast(unsigned int, f);
  u += 0x7FFFu + ((u >> 16) & 1u);          // RNE; inputs finite
  return (unsigned short)(u >> 16);
}
__device__ __forceinline__ float bf2f(unsigned short h){
  unsigned int u = ((unsigned int)h) << 16;
  return __builtin_bit_cast(float, u);
}

__device__ __forceinline__ void async16(void* lds, const void* g){
  __builtin_amdgcn_global_load_lds(
      (const __attribute__((address_space(1))) unsigned int*)g,
      (__attribute__((address_space(3))) unsigned int*)lds, 16, 0, 0);
}

#define MFMA16(d, va, vb) \
  d = __builtin_amdgcn_mfma_f32_16x16x32_bf16(va, vb, d, 0, 0, 0)

// ---------------- fp32 -> bf16 convert, 3 sources ----------------
__global__ __launch_bounds__(256) void cvt3(const float* __restrict__ a0,
                                            const float* __restrict__ a1,
                                            const float* __restrict__ a2,
                                            unsigned short* __restrict__ out,
                                            int n4_per){
  const float* src = blockIdx.y == 0 ? a0 : (blockIdx.y == 1 ? a1 : a2);
  unsigned short* dst = out + (size_t)blockIdx.y * (size_t)n4_per * 4;
  int i = blockIdx.x * 256 + threadIdx.x;
  if (i < n4_per){
    floatx4 f = ((const floatx4*)src)[i];
    ushortx4 o;
    o.x = f2bf(f.x); o.y = f2bf(f.y); o.z = f2bf(f.z); o.w = f2bf(f.w);
    *(ushortx4*)(dst + (size_t)i * 4) = o;
  }
}

// ---------------- mask [2048][2048] int32 -> bitmask (512 KB) ----------------
__global__ __launch_bounds__(256) void pack_mask(const int* __restrict__ m,
                                                 unsigned long long* __restrict__ bits){
  int t = blockIdx.x * 256 + threadIdx.x;          // 65536 words
  const int4* p = (const int4*)(m + (size_t)t * 64);
  unsigned long long w = 0;
  #pragma unroll
  for (int jj = 0; jj < 16; jj++){
    int4 v = p[jj];
    w |= (unsigned long long)(v.x != 0) << (jj * 4 + 0);
    w |= (unsigned long long)(v.y != 0) << (jj * 4 + 1);
    w |= (unsigned long long)(v.z != 0) << (jj * 4 + 2);
    w |= (unsigned long long)(v.w != 0) << (jj * 4 + 3);
  }
  bits[t] = w;
}

// ---------------- NT GEMM: C[m,n] = sum_k A[m,k]*B[n,k], all bf16 in ----------------
// Tile 256x256, BK=64, 512 threads = 8 waves (wm=wave>>2 in M, wn=wave&3 in N);
// per-wave 128x64 output = acc[8][4] of 16x16x32 MFMAs.
// LDS 128 KB: [dbuf][A|B][khalf] 16 KB units, rows of 64 B (32 bf16).
// Chunk swizzle: logical chunk c of row r stored at physical slot c^((r>>1)&3).
// ds_read_b128 slot for lane = 4*(lm&1) + (qd ^ ((lm>>1)&3)): every
// consecutive-8-lane group covers all 8 slots of a 128B bank row -> 0
// conflicts. Staging is linear-LDS global_load_lds with the inverse swizzle
// applied to the per-lane GLOBAL address (both-sides-or-neither rule).
// Schedule per K-tile t (4 phases, read dbuf rb=t&1):
//   p1: stage A-k1(t+1)->sb  | read a(k0,mi0-3)+b(k0) | lgkm0+bar | 16 MFMA
//   p2: stage B-k0(t+2)->rb  | read a(k0,mi4-7)       | lgkm0+bar | 16 MFMA
//   p3: stage A-k0(t+2)->rb  | read a(k1,mi0-3)+b(k1) | lgkm0+bar | 16 MFMA
//   p4: stage B-k1(t+2)->rb  | read a(k1,mi4-7)  | vmcnt(6)+lgkm0+bar | 16 MFMA
// vmcnt(6) at p4 confirms ALL 4 units of t+1 (8 loads), leaves 3 units of
// t+2 in flight (never drains in main loop).
// EPI 0: store bf16. EPI 1: mask-bit ? v/32 : -inf, store bf16. EPI 2: fp32.
template<int EPI>
__global__ __launch_bounds__(512, 2) void gemm_nt(
    const unsigned short* __restrict__ A, long strideA,
    const unsigned short* __restrict__ B, long strideB,
    void* __restrict__ Out, long strideOutBytes,
    const unsigned long long* __restrict__ mbits,
    int K, int gx, int gy)
{
  __shared__ __attribute__((aligned(16))) char Lds[131072];
  const int tid = threadIdx.x;
  const int lane = tid & 63, wave = tid >> 6;

  // XCD-aware decode: L%8 = XCD; all gx n-tiles of one A-strip on one XCD.
  int L = blockIdx.x;
  int xcd = L & 7, tt = L >> 3;
  int x = tt % gx;
  int strip = xcd + ((tt / gx) << 3);
  int y = strip % gy, z = strip / gy;
  const int m0 = y << 8, n0 = x << 8;
  const int Nn = gx << 8;

  const unsigned short* Az = A + (size_t)z * strideA;
  const unsigned short* Bz = B + (size_t)z * strideB;

  // Staging: unit = 16 KB = 1024 slots of 16B; thread covers slots tid and
  // tid+512. slot s: r = s>>2 (row; +128 for the second), cs = s&3,
  // logical chunk c = cs ^ ((r>>1)&3)  [invariant under r+128].
  const long rowb  = (long)K * 2;       // bytes per A/B row
  const long rs128 = rowb << 7;         // 128 rows
  const int r0 = tid >> 2;
  const int c0 = (tid & 3) ^ ((r0 >> 1) & 3);
  const char* pA0 = (const char*)Az + (size_t)(m0 + r0) * rowb + (c0 << 4);      // k-half 0
  const char* pA1 = pA0 + 64;                                                    // k-half 1
  const char* pB0 = (const char*)Bz + (size_t)(n0 + r0) * rowb + (c0 << 4);
  const char* pB1 = pB0 + 64;
  const int stg = tid << 4;

  auto stageU = [&](const char*& g, int ldsoff){
    async16(Lds + ldsoff + stg,        g);
    async16(Lds + ldsoff + stg + 8192, g + rs128);
    g += 128;                           // advance one K-tile (BK=64 bf16)
  };

  // Fragment reads: row = (warp base) + mi*16 + lm, logical chunk qd at
  // physical slot qd ^ ((row>>1)&3) = qd ^ ((lm>>1)&3).
  const int lm = lane & 15, qd = lane >> 4;
  const int wm = wave >> 2, wn = wave & 3;          // 2 (M) x 4 (N)
  const int fsw  = (qd ^ ((lm >> 1) & 3)) << 4;
  const int aoff = ((wm << 7) + lm) * 64 + fsw;               // + mi*1024 + kh*16384 + dbuf
  const int boff = 32768 + ((wn << 6) + lm) * 64 + fsw;       // + ni*1024 + kh*16384 + dbuf

  floatx4 acc[8][4];
  floatx4 zero4 = {0.f, 0.f, 0.f, 0.f};
  #pragma unroll
  for (int a = 0; a < 8; a++)
    #pragma unroll
    for (int b = 0; b < 4; b++) acc[a][b] = zero4;

  const int NK = K >> 6;

  // Prologue: tile0 all 4 units, tile1 {B-k0, A-k0, B-k1} (A-k1(1) comes at
  // t=0.p1). vmcnt(6) confirms tile0's 8 loads, leaves tile1's 6 in flight.
  stageU(pB0, 32768);                     // B-k0(0) dbuf0
  stageU(pA0, 0);                         // A-k0(0)
  stageU(pB1, 32768 + 16384);             // B-k1(0)
  stageU(pA1, 16384);                     // A-k1(0)
  stageU(pB0, 65536 + 32768);             // B-k0(1) dbuf1
  stageU(pA0, 65536);                     // A-k0(1)
  stageU(pB1, 65536 + 32768 + 16384);     // B-k1(1)
  asm volatile("s_waitcnt vmcnt(6)\n\ts_barrier" ::: "memory");

  short8 a[4], b[4];
  for (int t = 0; t < NK; ++t){
    const int rb = (t & 1) << 16;         // read dbuf (and t+2 stage dbuf)
    const int sb = rb ^ 65536;            // t+1 stage dbuf

    // ---- phase 1: kh=0, mi 0-3 (+ all B kh=0) ----
    if (t + 1 < NK) stageU(pA1, sb + 16384);
    #pragma unroll
    for (int j = 0; j < 4; j++) a[j] = *(const short8*)(Lds + rb + aoff + j * 1024);
    #pragma unroll
    for (int n = 0; n < 4; n++) b[n] = *(const short8*)(Lds + rb + boff + n * 1024);
    asm volatile("s_waitcnt lgkmcnt(0)\n\ts_barrier" ::: "memory");
    __builtin_amdgcn_sched_barrier(0);
    __builtin_amdgcn_s_setprio(1);
    #pragma unroll
    for (int j = 0; j < 4; j++)
      #pragma unroll
      for (int n = 0; n < 4; n++) MFMA16(acc[j][n], a[j], b[n]);
    __builtin_amdgcn_s_setprio(0);

    // ---- phase 2: kh=0, mi 4-7 ----
    if (t + 2 < NK) stageU(pB0, rb + 32768);
    #pragma unroll
    for (int j = 0; j < 4; j++) a[j] = *(const short8*)(Lds + rb + aoff + (4 + j) * 1024);
    asm volatile("s_waitcnt lgkmcnt(0)\n\ts_barrier" ::: "memory");
    __builtin_amdgcn_sched_barrier(0);
    __builtin_amdgcn_s_setprio(1);
    #pragma unroll
    for (int j = 0; j < 4; j++)
      #pragma unroll
      for (int n = 0; n < 4; n++) MFMA16(acc[4 + j][n], a[j], b[n]);
    __builtin_amdgcn_s_setprio(0);

    // ---- phase 3: kh=1, mi 0-3 (+ all B kh=1) ----
    if (t + 2 < NK) stageU(pA0, rb);
    #pragma unroll
    for (int j = 0; j < 4; j++) a[j] = *(const short8*)(Lds + rb + 16384 + aoff + j * 1024);
    #pragma unroll
    for (int n = 0; n < 4; n++) b[n] = *(const short8*)(Lds + rb + 16384 + boff + n * 1024);
    asm volatile("s_waitcnt lgkmcnt(0)\n\ts_barrier" ::: "memory");
    __builtin_amdgcn_sched_barrier(0);
    __builtin_amdgcn_s_setprio(1);
    #pragma unroll
    for (int j = 0; j < 4; j++)
      #pragma unroll
      for (int n = 0; n < 4; n++) MFMA16(acc[j][n], a[j], b[n]);
    __builtin_amdgcn_s_setprio(0);

    // ---- phase 4: kh=1, mi 4-7; the one counted vmcnt per K-tile ----
    if (t + 2 < NK) stageU(pB1, rb + 32768 + 16384);
    #pragma unroll
    for (int j = 0; j < 4; j++) a[j] = *(const short8*)(Lds + rb + 16384 + aoff + (4 + j) * 1024);
    if (t + 2 < NK)
      asm volatile("s_waitcnt vmcnt(6) lgkmcnt(0)\n\ts_barrier" ::: "memory");
    else
      asm volatile("s_waitcnt vmcnt(0) lgkmcnt(0)\n\ts_barrier" ::: "memory");
    __builtin_amdgcn_sched_barrier(0);
    __builtin_amdgcn_s_setprio(1);
    #pragma unroll
    for (int j = 0; j < 4; j++)
      #pragma unroll
      for (int n = 0; n < 4; n++) MFMA16(acc[4 + j][n], a[j], b[n]);
    __builtin_amdgcn_s_setprio(0);
  }

  // Epilogue. C/D layout: col = lane&15, row = (lane>>4)*4 + i  (m89/m91).
  char* OutZ = (char*)Out + (size_t)z * strideOutBytes;
  const int colbase = n0 + (wn << 6);
  if constexpr (EPI == 1){
    const int wcol = colbase >> 6;
    #pragma unroll
    for (int mi = 0; mi < 8; mi++){
      #pragma unroll
      for (int i = 0; i < 4; i++){
        int row = m0 + (wm << 7) + mi * 16 + qd * 4 + i;
        unsigned long long w = mbits[(size_t)row * (NT / 64) + wcol];
        unsigned short* po = (unsigned short*)OutZ + (size_t)row * Nn + colbase;
        #pragma unroll
        for (int ni = 0; ni < 4; ni++){
          float vv = acc[mi][ni][i];
          float s = ((w >> (ni * 16 + lm)) & 1ull) ? vv * 0.03125f : -INFINITY;
          po[ni * 16 + lm] = f2bf(s);
        }
      }
    }
  } else {
    #pragma unroll
    for (int mi = 0; mi < 8; mi++){
      #pragma unroll
      for (int i = 0; i < 4; i++){
        int row = m0 + (wm << 7) + mi * 16 + qd * 4 + i;
        #pragma unroll
        for (int ni = 0; ni < 4; ni++){
          int col = colbase + ni * 16 + lm;
          float vv = acc[mi][ni][i];
          if constexpr (EPI == 0)
            ((unsigned short*)OutZ)[(size_t)row * Nn + col] = f2bf(vv);
          else
            ((float*)OutZ)[(size_t)row * Nn + col] = vv;
        }
      }
    }
  }
}

// ---------------- bf16 transpose (per batch): [rows][cols] -> [cols][rows] ----------------
__global__ __launch_bounds__(256) void transpose_bf16(const unsigned short* __restrict__ in,
                                                      unsigned short* __restrict__ out,
                                                      int rows, int cols){
  __shared__ __attribute__((aligned(16))) unsigned short tile[64][72];
  const unsigned short* ib = in + (size_t)blockIdx.z * rows * cols;
  unsigned short* ob = out + (size_t)blockIdx.z * rows * cols;
  int r0 = blockIdx.x * 64;
  int c0 = blockIdx.y * 64;
  int tid = threadIdx.x;
  #pragma unroll
  for (int i = 0; i < 2; i++){
    int id = tid + i * 256;
    int r = id >> 3, c = (id & 7) * 8;
    ushortx8 v = *(const ushortx8*)(ib + (size_t)(r0 + r) * cols + c0 + c);
    *(ushortx8*)&tile[r][c] = v;
  }
  __syncthreads();
  #pragma unroll
  for (int i = 0; i < 2; i++){
    int id = tid + i * 256;
    int r = id >> 3, c = (id & 7) * 8;
    ushortx8 v;
    #pragma unroll
    for (int j = 0; j < 8; j++) v[j] = tile[c + j][r];
    *(ushortx8*)(ob + (size_t)(c0 + r) * rows + r0 + c) = v;
  }
}

// ---------------- row softmax, in place over bf16 scores ----------------
__global__ __launch_bounds__(256) void softmax_rows(unsigned short* __restrict__ S){
  size_t row = blockIdx.x;
  unsigned short* p = S + row * NT;
  int tid = threadIdx.x;
  ushortx8 v = *(const ushortx8*)(p + tid * 8);
  float f[8];
  #pragma unroll
  for (int j = 0; j < 8; j++) f[j] = bf2f(v[j]);
  float mx = f[0];
  #pragma unroll
  for (int j = 1; j < 8; j++) mx = fmaxf(mx, f[j]);
  #pragma unroll
  for (int off = 32; off > 0; off >>= 1) mx = fmaxf(mx, __shfl_xor(mx, off, 64));
  __shared__ float redm[4], reds[4];
  int lane = tid & 63, wv = tid >> 6;
  if (lane == 0) redm[wv] = mx;
  __syncthreads();
  mx = fmaxf(fmaxf(redm[0], redm[1]), fmaxf(redm[2], redm[3]));
  float e[8]; float se = 0.f;
  #pragma unroll
  for (int j = 0; j < 8; j++){ e[j] = __expf(f[j] - mx); se += e[j]; }
  #pragma unroll
  for (int off = 32; off > 0; off >>= 1) se += __shfl_xor(se, off, 64);
  if (lane == 0) reds[wv] = se;
  __syncthreads();
  se = reds[0] + reds[1] + reds[2] + reds[3];
  float inv = 1.f / se;
  ushortx8 o;
  #pragma unroll
  for (int j = 0; j < 8; j++) o[j] = f2bf(e[j] * inv);
  *(ushortx8*)(p + tid * 8) = o;
}

extern "C" void kernel_launch(void* const* d_in, const int* in_sizes, int n_in,
                              void* d_out, int out_size, void* d_ws, size_t ws_size,
                              hipStream_t stream){
  const float* q  = (const float*)d_in[0];
  const float* k  = (const float*)d_in[1];
  const float* v  = (const float*)d_in[2];
  const int* mask = (const int*)d_in[3];
  const float* Wq = (const float*)d_in[4];
  const float* Wk = (const float*)d_in[5];
  const float* Wv = (const float*)d_in[6];

  const size_t BTE = (size_t)NB * NT * NE;     // 16,777,216
  unsigned short* ws   = (unsigned short*)d_ws;
  unsigned short* QKVp = ws;                                    // [3][B*T][E]
  unsigned short* VpT  = ws + 3 * BTE;                          // [B][E][T]
  unsigned short* Sb   = ws + 3 * BTE + BTE;                    // [B][T][T]
  unsigned short* Qin  = ws + 3 * BTE;                          // aliases VpT+Sb (3*BTE)
  unsigned short* Wb   = ws + 3 * BTE + BTE + (size_t)NB * NT * NT;  // [3][E][E]
  unsigned long long* mbits = (unsigned long long*)(Wb + (size_t)3 * NE * NE);

  unsigned short* Qp = QKVp;
  unsigned short* Kp = QKVp + BTE;
  unsigned short* Vp = QKVp + 2 * BTE;

  // 1) fp32 -> bf16: inputs q,k,v (Qin aliases the region later used by VpT|Sb)
  cvt3<<<dim3(16384, 3), 256, 0, stream>>>(q, k, v, Qin, (int)(BTE / 4));
  // 2) weights -> bf16
  cvt3<<<dim3(1024, 3), 256, 0, stream>>>(Wq, Wk, Wv, Wb, NE * NE / 4);
  // 3) mask -> bitmask
  pack_mask<<<256, 256, 0, stream>>>(mask, mbits);

  // 4) projections: [3 x] (16384 x 1024 x 1024); gx=4, gy=64, gz=3
  gemm_nt<0><<<768, 512, 0, stream>>>(
      Qin, (long)BTE, Wb, (long)NE * NE,
      QKVp, (long)BTE * 2, nullptr, NE, 4, 64);

  // 5) V -> V^T per batch (overwrites Qin's q-part, no longer needed)
  transpose_bf16<<<dim3(32, 16, 8), 256, 0, stream>>>(Vp, VpT, NT, NE);

  // 6) S = mask ? QK^T/32 : -inf; gx=8, gy=8, gz=8
  gemm_nt<1><<<512, 512, 0, stream>>>(
      Qp, (long)NT * NE, Kp, (long)NT * NE,
      Sb, (long)NT * NT * 2, mbits, NE, 8, 8);

  // 7) softmax rows, in place
  softmax_rows<<<dim3(NB * NT), 256, 0, stream>>>(Sb);

  // 8) O = P V; gx=4, gy=8, gz=8, fp32 out
  gemm_nt<2><<<256, 512, 0, stream>>>(
      Sb, (long)NT * NT, VpT, (long)NE * NT,
      d_out, (long)NT * NE * 4, nullptr, NT, 4, 8);
}